// Round 1
// baseline (3716.661 us; speedup 1.0000x reference)
//
#include <hip/hip_runtime.h>
#include <cstdint>

// ---------------------------------------------------------------------------
// JukeboxAutoEncoder fp32, round 8.
// convs: unchanged from round 7 (512-thr, 8 waves x 8 wave-uniform co).
// vq_dots: rewritten. Chunked codebook (4 x 16 dims) so per-thread state is
//   acc[32] + 16-float cb chunk (~72 VGPR, no AGPR shadow-copies); argmin via
//   fmin butterfly + ballot/ffs (6 bpermute/token instead of 12, ~12 fewer
//   VALU/token). launch_bounds(256,6).
// Output layout (flat f32): x_hat[262144] | loss_vq[1] | ids[32768] | sim[16777216]
// ---------------------------------------------------------------------------

#define OFF_LOSS 262144
#define OFF_IDS  262145
#define OFF_SIM  294913

// ---------------- down0: (B,65536,1) -> (B,32768,64), K=4 stride2, relu ----
__global__ __launch_bounds__(256) void down0_kernel(
    const float* __restrict__ x, const float* __restrict__ w,
    const float* __restrict__ bias, float* __restrict__ y)
{
  int idx = blockIdx.x * 256 + threadIdx.x;   // enumerates (b, t, co)
  int co = idx & 63;
  int r  = idx >> 6;
  int t  = r & 32767;
  int b  = r >> 15;
  const float* xb = x + (size_t)b * 65536;
  float acc = bias[co];
  #pragma unroll
  for (int k = 0; k < 4; ++k) {
    int gt = 2 * t - 1 + k;
    float xv = ((unsigned)gt < 65536u) ? xb[gt] : 0.f;
    acc += xv * w[k * 64 + co];
  }
  y[(size_t)idx] = fmaxf(acc, 0.f);
}

// ---------------- conv3: K=3, dil DIL, 64->64, relu, optional +res --------
// 512 thr = 8 waves; wave wv owns co0 = wv*8 (wave-uniform -> s_load weights);
// lane covers t = t0 + TPL*lane + i, i<TPL. grid (T/TT, 4).
template <int DIL, bool HAS_RES, int TT>
__global__ __launch_bounds__(512, 8) void conv3_kernel(
    const float* __restrict__ x, const float* __restrict__ w,
    const float* __restrict__ bias, const float* res,
    float* y, int T)
{
  constexpr int TPL = TT / 64;               // 1 or 2 t per lane
  constexpr int XT  = TT + 2 * DIL;
  constexpr int XS0 = (XT + 3) & ~3;
  constexpr int XS  = (XS0 % 8 == 4) ? XS0 : XS0 + 4;  // 8B-align rows, break pow2
  constexpr int NV  = TPL + 2 * DIL;
  __shared__ float xs[64 * XS];
  const int tid  = threadIdx.x;
  const int lane = tid & 63;
  const int b    = blockIdx.y;
  const int t0   = blockIdx.x * TT;
  const int wv   = __builtin_amdgcn_readfirstlane(tid >> 6);
  const int co0  = __builtin_amdgcn_readfirstlane(wv * 8);

  const float* xb = x + (size_t)b * T * 64;
  for (int e = tid; e < 16 * XT; e += 512) { // transpose to [ci][t]
    int tl = e >> 4, cq = (e & 15) * 4;
    int gt = t0 - DIL + tl;
    float4 v = make_float4(0.f, 0.f, 0.f, 0.f);
    if ((unsigned)gt < (unsigned)T) v = *(const float4*)&xb[(size_t)gt * 64 + cq];
    xs[(cq + 0) * XS + tl] = v.x;
    xs[(cq + 1) * XS + tl] = v.y;
    xs[(cq + 2) * XS + tl] = v.z;
    xs[(cq + 3) * XS + tl] = v.w;
  }
  __syncthreads();

  float acc[TPL][8] = {};
  const float* wb = w + co0;                 // w[k][ci][co0..co0+7]
  const int tb = TPL * lane;
  for (int ci = 0; ci < 64; ++ci) {
    const float* xr = xs + ci * XS + tb;
    float xv[NV];
    if constexpr (TPL == 2) {                // 8B-aligned -> ds_read_b64
      const float2* p2 = (const float2*)xr;
      #pragma unroll
      for (int q = 0; q < NV / 2; ++q) { float2 v = p2[q]; xv[2*q] = v.x; xv[2*q+1] = v.y; }
    } else {
      #pragma unroll
      for (int j = 0; j < NV; ++j) xv[j] = xr[j];
    }
    const float* w0 = wb + (0 * 64 + ci) * 64;
    const float* w1 = wb + (1 * 64 + ci) * 64;
    const float* w2 = wb + (2 * 64 + ci) * 64;
    #pragma unroll
    for (int j = 0; j < 8; ++j) {
      float c0 = w0[j], c1 = w1[j], c2 = w2[j];
      #pragma unroll
      for (int i = 0; i < TPL; ++i)
        acc[i][j] = fmaf(xv[i], c0, fmaf(xv[i + DIL], c1, fmaf(xv[i + 2 * DIL], c2, acc[i][j])));
    }
  }

  float bs[8];
  #pragma unroll
  for (int j = 0; j < 8; ++j) bs[j] = bias[co0 + j];
  #pragma unroll
  for (int i = 0; i < TPL; ++i) {
    size_t o = ((size_t)b * T + t0 + tb + i) * 64 + co0;
    float r[8];
    #pragma unroll
    for (int j = 0; j < 8; ++j) r[j] = fmaxf(acc[i][j] + bs[j], 0.f);
    if (HAS_RES) {
      float4 v0 = *(const float4*)&res[o];
      float4 v1 = *(const float4*)&res[o + 4];
      r[0] += v0.x; r[1] += v0.y; r[2] += v0.z; r[3] += v0.w;
      r[4] += v1.x; r[5] += v1.y; r[6] += v1.z; r[7] += v1.w;
    }
    *(float4*)&y[o]     = make_float4(r[0], r[1], r[2], r[3]);
    *(float4*)&y[o + 4] = make_float4(r[4], r[5], r[6], r[7]);
  }
}

// ---------------- down2: K=4 stride2, 64->64, relu ------------------------
// 512 thr = 8 waves; wave owns co0 = wv*8; lane = out t (64/block).
// grid (Tout/64, 4). Reads 4 consecutive floats at 2*lane -> 2x ds_read_b64.
__global__ __launch_bounds__(512, 8) void down2_kernel(
    const float* __restrict__ x, const float* __restrict__ w,
    const float* __restrict__ bias, float* __restrict__ y, int Tin)
{
  constexpr int XT = 130, XS = 132;          // XS mod 8 == 4
  __shared__ float xs[64 * XS];
  const int tid  = threadIdx.x;
  const int lane = tid & 63;
  const int b    = blockIdx.y;
  const int t0   = blockIdx.x * 64;
  const int Tout = Tin >> 1;
  const int wv   = __builtin_amdgcn_readfirstlane(tid >> 6);
  const int co0  = __builtin_amdgcn_readfirstlane(wv * 8);

  const float* xb = x + (size_t)b * Tin * 64;
  for (int e = tid; e < 16 * XT; e += 512) {
    int tl = e >> 4, cq = (e & 15) * 4;
    int gt = 2 * t0 - 1 + tl;
    float4 v = make_float4(0.f, 0.f, 0.f, 0.f);
    if ((unsigned)gt < (unsigned)Tin) v = *(const float4*)&xb[(size_t)gt * 64 + cq];
    xs[(cq + 0) * XS + tl] = v.x;
    xs[(cq + 1) * XS + tl] = v.y;
    xs[(cq + 2) * XS + tl] = v.z;
    xs[(cq + 3) * XS + tl] = v.w;
  }
  __syncthreads();

  float acc[8] = {};
  const float* wb = w + co0;
  for (int ci = 0; ci < 64; ++ci) {
    const float2* p2 = (const float2*)(xs + ci * XS + 2 * lane);
    float2 v0 = p2[0], v1 = p2[1];
    float a0 = v0.x, a1 = v0.y, a2 = v1.x, a3 = v1.y;
    const float* w0 = wb + (0 * 64 + ci) * 64;
    const float* w1 = wb + (1 * 64 + ci) * 64;
    const float* w2 = wb + (2 * 64 + ci) * 64;
    const float* w3 = wb + (3 * 64 + ci) * 64;
    #pragma unroll
    for (int j = 0; j < 8; ++j)
      acc[j] = fmaf(a0, w0[j], fmaf(a1, w1[j], fmaf(a2, w2[j], fmaf(a3, w3[j], acc[j]))));
  }

  size_t o = ((size_t)b * Tout + t0 + lane) * 64 + co0;
  #pragma unroll
  for (int q = 0; q < 2; ++q) {
    float4 rr;
    rr.x = fmaxf(acc[4*q+0] + bias[co0 + 4*q+0], 0.f);
    rr.y = fmaxf(acc[4*q+1] + bias[co0 + 4*q+1], 0.f);
    rr.z = fmaxf(acc[4*q+2] + bias[co0 + 4*q+2], 0.f);
    rr.w = fmaxf(acc[4*q+3] + bias[co0 + 4*q+3], 0.f);
    *(float4*)&y[o + 4 * q] = rr;
  }
}

// ---------------- up: conv_transpose K=4 stride2, 64->64, relu ------------
// y[2u] = relu(b + w0^T x[u-1] + w2^T x[u]); y[2u+1] = relu(b + w1^T x[u] + w3^T x[u+1])
// 512 thr = 8 waves; wave owns co0 = wv*8; lane = u (64 u = 128 out t).
// grid (Tout/128, 4).
__global__ __launch_bounds__(512, 8) void up_kernel(
    const float* __restrict__ x, const float* __restrict__ w,
    const float* __restrict__ bias, float* __restrict__ y, int Tin)
{
  constexpr int XT = 66, XS = 68;            // XS mod 8 == 4
  __shared__ float xs[64 * XS];
  const int tid  = threadIdx.x;
  const int lane = tid & 63;
  const int b    = blockIdx.y;
  const int u0   = blockIdx.x * 64;
  const int Tout = Tin << 1;
  const int wv   = __builtin_amdgcn_readfirstlane(tid >> 6);
  const int co0  = __builtin_amdgcn_readfirstlane(wv * 8);

  const float* xb = x + (size_t)b * Tin * 64;
  for (int e = tid; e < 16 * XT; e += 512) {
    int ul = e >> 4, cq = (e & 15) * 4;
    int gu = u0 - 1 + ul;
    float4 v = make_float4(0.f, 0.f, 0.f, 0.f);
    if ((unsigned)gu < (unsigned)Tin) v = *(const float4*)&xb[(size_t)gu * 64 + cq];
    xs[(cq + 0) * XS + ul] = v.x;
    xs[(cq + 1) * XS + ul] = v.y;
    xs[(cq + 2) * XS + ul] = v.z;
    xs[(cq + 3) * XS + ul] = v.w;
  }
  __syncthreads();

  float acce[8] = {}, acco[8] = {};
  const float* wb = w + co0;
  for (int ci = 0; ci < 64; ++ci) {
    const float* xr = xs + ci * XS + lane;
    float a0 = xr[0], a1 = xr[1], a2 = xr[2];  // x[u-1], x[u], x[u+1]
    const float* w0 = wb + (0 * 64 + ci) * 64;
    const float* w1 = wb + (1 * 64 + ci) * 64;
    const float* w2 = wb + (2 * 64 + ci) * 64;
    const float* w3 = wb + (3 * 64 + ci) * 64;
    #pragma unroll
    for (int j = 0; j < 8; ++j) {
      acce[j] = fmaf(a0, w0[j], fmaf(a1, w2[j], acce[j]));
      acco[j] = fmaf(a1, w1[j], fmaf(a2, w3[j], acco[j]));
    }
  }

  size_t oe = ((size_t)b * Tout + 2 * (u0 + lane)) * 64 + co0;
  size_t oo = oe + 64;
  #pragma unroll
  for (int q = 0; q < 2; ++q) {
    float4 re, ro;
    re.x = fmaxf(acce[4*q+0] + bias[co0 + 4*q+0], 0.f);
    re.y = fmaxf(acce[4*q+1] + bias[co0 + 4*q+1], 0.f);
    re.z = fmaxf(acce[4*q+2] + bias[co0 + 4*q+2], 0.f);
    re.w = fmaxf(acce[4*q+3] + bias[co0 + 4*q+3], 0.f);
    ro.x = fmaxf(acco[4*q+0] + bias[co0 + 4*q+0], 0.f);
    ro.y = fmaxf(acco[4*q+1] + bias[co0 + 4*q+1], 0.f);
    ro.z = fmaxf(acco[4*q+2] + bias[co0 + 4*q+2], 0.f);
    ro.w = fmaxf(acco[4*q+3] + bias[co0 + 4*q+3], 0.f);
    *(float4*)&y[oe + 4 * q] = re;
    *(float4*)&y[oo + 4 * q] = ro;
  }
}

// ---------------- proj: K=3 dil1, 64->1, linear ---------------------------
__global__ __launch_bounds__(256) void proj_kernel(
    const float* __restrict__ x, const float* __restrict__ w,
    const float* __restrict__ bias, float* __restrict__ out)
{
  const int lane = threadIdx.x & 63;
  const int wid  = (blockIdx.x * 256 + threadIdx.x) >> 6;  // 4096 waves
  const float w0 = w[lane], w1 = w[64 + lane], w2 = w[128 + lane];
  const float bb = bias[0];
  size_t base = (size_t)wid * 64;
  for (int i = 0; i < 64; ++i) {
    size_t tau = base + i;
    int b = (int)(tau >> 16);
    int t = (int)(tau & 65535);
    const float* xb = x + ((size_t)b * 65536) * 64;
    float pm = (t > 0)     ? xb[(size_t)(t - 1) * 64 + lane] : 0.f;
    float pc =               xb[(size_t)t * 64 + lane];
    float pp = (t < 65535) ? xb[(size_t)(t + 1) * 64 + lane] : 0.f;
    float s = pm * w0 + pc * w1 + pp * w2;
    #pragma unroll
    for (int off = 32; off; off >>= 1) s += __shfl_down(s, off);
    if (lane == 0) out[tau] = s + bb;
  }
}

// ---------------- nz: per-token sum of squares ----------------------------
__global__ __launch_bounds__(256) void nz_kernel(
    const float* __restrict__ ze, float* __restrict__ nz)
{
  int lane = threadIdx.x & 63;
  int tok  = (blockIdx.x * 256 + threadIdx.x) >> 6;
  float v = ze[(size_t)tok * 64 + lane];
  float s = v * v;
  #pragma unroll
  for (int off = 32; off; off >>= 1) s += __shfl_down(s, off);
  if (lane == 0) nz[tok] = s;
}

// ---------------- vq_dots: chunked-cb version -----------------------------
// Block covers 32 tokens (z tile in LDS, broadcast reads) x 256 cb entries.
// Per thread: acc[32] + 16-float cb chunk (4 chunks over d) -> ~72 VGPR,
// no AGPR shadow-copies. Argmin: fmin butterfly + ballot/ffs (6 bpermute/tok).
#define VQA_TOKS 32
__global__ __launch_bounds__(256, 6) void vq_dots_kernel(
    const float* __restrict__ ze, const float* __restrict__ cb,
    const float* __restrict__ nzbuf, float* __restrict__ sim_out,
    float2* __restrict__ pmin)
{
  __shared__ float zs[VQA_TOKS * 64];        // 8 KB
  const int tid = threadIdx.x;
  {
    const float4* src = (const float4*)(ze + (size_t)blockIdx.x * VQA_TOKS * 64);
    float4* dst = (float4*)zs;
    dst[tid]       = src[tid];
    dst[tid + 256] = src[tid + 256];
  }
  const int c = blockIdx.y * 256 + tid;
  const float4* cb4 = (const float4*)(cb + (size_t)c * 64);
  const int wvid = tid >> 6;

  float acc[VQA_TOKS];
  #pragma unroll
  for (int t = 0; t < VQA_TOKS; ++t) acc[t] = 0.f;
  float ne = 0.f;
  __syncthreads();

  #pragma unroll
  for (int q = 0; q < 4; ++q) {              // 16 dims per chunk
    float4 w0 = cb4[4 * q + 0];
    float4 w1 = cb4[4 * q + 1];
    float4 w2 = cb4[4 * q + 2];
    float4 w3 = cb4[4 * q + 3];
    ne += w0.x * w0.x + w0.y * w0.y + w0.z * w0.z + w0.w * w0.w
        + w1.x * w1.x + w1.y * w1.y + w1.z * w1.z + w1.w * w1.w
        + w2.x * w2.x + w2.y * w2.y + w2.z * w2.z + w2.w * w2.w
        + w3.x * w3.x + w3.y * w3.y + w3.z * w3.z + w3.w * w3.w;
    const float4* zq4 = (const float4*)(zs + q * 16);  // +t*16 float4s per tok
    #pragma unroll
    for (int t = 0; t < VQA_TOKS; ++t) {     // LDS broadcast reads
      float4 z0 = zq4[t * 16 + 0];
      float4 z1 = zq4[t * 16 + 1];
      float4 z2 = zq4[t * 16 + 2];
      float4 z3 = zq4[t * 16 + 3];
      acc[t] += z0.x * w0.x + z0.y * w0.y + z0.z * w0.z + z0.w * w0.w
              + z1.x * w1.x + z1.y * w1.y + z1.z * w1.z + z1.w * w1.w
              + z2.x * w2.x + z2.y * w2.y + z2.z * w2.z + z2.w * w2.w
              + z3.x * w3.x + z3.y * w3.y + z3.z * w3.z + z3.w * w3.w;
    }
  }
  const float rsne = 1.f / sqrtf(ne);
  const int cbase = blockIdx.y * 256 + wvid * 64;   // c of lane 0 in this wave

  #pragma unroll
  for (int t = 0; t < VQA_TOKS; ++t) {
    const int tok = blockIdx.x * VQA_TOKS + t;
    const float nzv = nzbuf[tok];
    const float dot = acc[t];
    const float dist = (-2.f * dot + nzv) + ne;
    sim_out[(size_t)tok * 512 + c] = dot * (1.f / sqrtf(nzv)) * rsne;

    float md = dist;
    #pragma unroll
    for (int off = 32; off; off >>= 1) md = fminf(md, __shfl_xor(md, off));
    unsigned long long mk = __ballot(dist == md);
    if ((tid & 63) == 0) {
      int lmin = __ffsll(mk) - 1;            // lowest lane == lowest c (tie-break)
      pmin[tok * 8 + blockIdx.y * 4 + wvid] = make_float2(md, (float)(cbase + lmin));
    }
  }
}

// ---------------- vq_finish: cross-partial argmin, z_q, ids, loss ---------
__global__ __launch_bounds__(256) void vq_finish_kernel(
    const float* __restrict__ ze, const float* __restrict__ cb,
    const float2* __restrict__ pmin, float* __restrict__ zq,
    float* __restrict__ ids_out, float* __restrict__ blocksum)
{
  const int tid = threadIdx.x;
  const int lane = tid & 63, wvid = tid >> 6;
  float lloss = 0.f;
  for (int it = 0; it < 16; ++it) {
    const int tok = blockIdx.x * 64 + wvid * 16 + it;
    float bd = 1e30f; int bi = 0;
    #pragma unroll
    for (int p = 0; p < 8; ++p) {
      float2 pr = pmin[tok * 8 + p];
      float d = pr.x; int i = (int)pr.y;
      if (d < bd || (d == bd && i < bi)) { bd = d; bi = i; }
    }
    float zev = ze[(size_t)tok * 64 + lane];
    float cv  = cb[(size_t)bi * 64 + lane];
    float df = zev - cv;
    float s = df * df;
    #pragma unroll
    for (int off = 32; off; off >>= 1) s += __shfl_down(s, off);
    zq[(size_t)tok * 64 + lane] = cv;
    if (lane == 0) { ids_out[tok] = (float)bi; lloss += sqrtf(s); }
  }
  __shared__ float ls[4];
  if (lane == 0) ls[wvid] = lloss;
  __syncthreads();
  if (tid == 0) blocksum[blockIdx.x] = ls[0] + ls[1] + ls[2] + ls[3];
}

__global__ void loss_fin_kernel(const float* __restrict__ blocksum,
                                float* __restrict__ out)
{
  const int lane = threadIdx.x;  // 64 threads
  float s = 0.f;
  for (int i = lane; i < 512; i += 64) s += blocksum[i];
  #pragma unroll
  for (int off = 32; off; off >>= 1) s += __shfl_down(s, off);
  if (lane == 0) out[0] = 1.25f * s / 32768.f;
}

// ---------------------------------------------------------------------------
#define LAUNCH_CONV3(DILV, RESV, XP, WP, BP, RP, YP)                           \
  do {                                                                         \
    if (T >= 16384)                                                            \
      conv3_kernel<DILV, RESV, 128><<<dim3(T / 128, 4), 512, 0, stream>>>(     \
          XP, WP, BP, RP, YP, T);                                              \
    else                                                                       \
      conv3_kernel<DILV, RESV, 64><<<dim3(T / 64, 4), 512, 0, stream>>>(       \
          XP, WP, BP, RP, YP, T);                                              \
  } while (0)

extern "C" void kernel_launch(void* const* d_in, const int* in_sizes, int n_in,
                              void* d_out, int out_size, void* d_ws, size_t ws_size,
                              hipStream_t stream)
{
  const float* x       = (const float*)d_in[0];
  const float* w_down0 = (const float*)d_in[1];
  const float* b_down0 = (const float*)d_in[2];
  const float* w_down  = (const float*)d_in[3];
  const float* b_down  = (const float*)d_in[4];
  const float* w_res_e = (const float*)d_in[5];
  const float* b_res_e = (const float*)d_in[6];
  const float* cb      = (const float*)d_in[7];
  const float* w_res_d = (const float*)d_in[8];
  const float* b_res_d = (const float*)d_in[9];
  const float* w_up    = (const float*)d_in[10];
  const float* b_up    = (const float*)d_in[11];
  const float* w_proj  = (const float*)d_in[12];
  const float* b_proj  = (const float*)d_in[13];

  float* out = (float*)d_out;
  const size_t BUF = (size_t)4 * 65536 * 64;
  float*  bufA     = (float*)d_ws;
  float*  bufB     = bufA + BUF;
  float*  nzbuf    = bufB + BUF;
  float2* pmin     = (float2*)(nzbuf + 32768);
  float*  blocksum = (float*)(pmin + 32768 * 8);

  float* h = bufA;
  float* tmp = bufB;

  // ---- encoder ----
  down0_kernel<<<32768, 256, 0, stream>>>(x, w_down0, b_down0, h);
  int T = 32768;
  for (int blk = 0; blk < 3; ++blk) {
    if (blk > 0) {
      down2_kernel<<<dim3(T / 2 / 64, 4), 512, 0, stream>>>(
          h, w_down + (size_t)(blk - 1) * 4 * 64 * 64, b_down + (blk - 1) * 64, tmp, T);
      T >>= 1;
      float* s = h; h = tmp; tmp = s;
    }
    for (int r = 0; r < 4; ++r) {
      const float* w0p = w_res_e + (((size_t)blk * 4 + r) * 2 + 0) * 3 * 64 * 64;
      const float* w1p = w_res_e + (((size_t)blk * 4 + r) * 2 + 1) * 3 * 64 * 64;
      const float* b0p = b_res_e + (((size_t)blk * 4 + r) * 2 + 0) * 64;
      const float* b1p = b_res_e + (((size_t)blk * 4 + r) * 2 + 1) * 64;
      LAUNCH_CONV3(3, false, h, w0p, b0p, nullptr, tmp);
      LAUNCH_CONV3(1, true,  tmp, w1p, b1p, h, h);
    }
  }

  // ---- VQ (T == 8192, z_e in h; 32768 tokens) ----
  nz_kernel<<<8192, 256, 0, stream>>>(h, nzbuf);
  vq_dots_kernel<<<dim3(32768 / VQA_TOKS, 2), 256, 0, stream>>>(h, cb, nzbuf, out + OFF_SIM, pmin);
  vq_finish_kernel<<<512, 256, 0, stream>>>(h, cb, pmin, tmp, out + OFF_IDS, blocksum);
  loss_fin_kernel<<<1, 64, 0, stream>>>(blocksum, out + OFF_LOSS);
  { float* s = h; h = tmp; tmp = s; }  // h = z_q

  // ---- decoder ----
  for (int blk = 0; blk < 3; ++blk) {
    for (int r = 0; r < 4; ++r) {
      const float* w0p = w_res_d + (((size_t)blk * 4 + r) * 2 + 0) * 3 * 64 * 64;
      const float* w1p = w_res_d + (((size_t)blk * 4 + r) * 2 + 1) * 3 * 64 * 64;
      const float* b0p = b_res_d + (((size_t)blk * 4 + r) * 2 + 0) * 64;
      const float* b1p = b_res_d + (((size_t)blk * 4 + r) * 2 + 1) * 64;
      LAUNCH_CONV3(1, false, h, w0p, b0p, nullptr, tmp);
      LAUNCH_CONV3(3, true,  tmp, w1p, b1p, h, h);
    }
    up_kernel<<<dim3(2 * T / 128, 4), 512, 0, stream>>>(
        h, w_up + (size_t)blk * 4 * 64 * 64, b_up + blk * 64, tmp, T);
    T <<= 1;
    float* s = h; h = tmp; tmp = s;
  }

  // ---- final projection (T == 65536) ----
  proj_kernel<<<1024, 256, 0, stream>>>(h, w_proj, b_proj, out);
}

// Round 2
// 1626.057 us; speedup vs baseline: 2.2857x; 2.2857x over previous
//
#include <hip/hip_runtime.h>
#include <cstdint>

// ---------------------------------------------------------------------------
// JukeboxAutoEncoder fp32, round 9.
// convs: unchanged from round 7 (512-thr, 8 waves x 8 wave-uniform co).
// vq_dots: register-blocked GEMM. Block = 64 tok x 128 ent, per-thread 4x8
//   acc (32 VGPR, static idx, NO launch_bounds VGPR cap -- r8's (256,6) cap
//   forced acc[] to scratch: VGPR=40, 6.9 GB scratch HBM traffic, 1943 us).
//   Both operands LDS-transposed ([d][tok] s=68, [d][ent] s=132); inner loop
//   = 3 ds_read_b128 + 32 FMA. ne precomputed once. Argmin: local scan +
//   4-step (md,mi) shfl_xor butterfly in 16-lane group; 4 partials/token.
// Output layout (flat f32): x_hat[262144] | loss_vq[1] | ids[32768] | sim[16777216]
// ---------------------------------------------------------------------------

#define OFF_LOSS 262144
#define OFF_IDS  262145
#define OFF_SIM  294913

// ---------------- down0: (B,65536,1) -> (B,32768,64), K=4 stride2, relu ----
__global__ __launch_bounds__(256) void down0_kernel(
    const float* __restrict__ x, const float* __restrict__ w,
    const float* __restrict__ bias, float* __restrict__ y)
{
  int idx = blockIdx.x * 256 + threadIdx.x;   // enumerates (b, t, co)
  int co = idx & 63;
  int r  = idx >> 6;
  int t  = r & 32767;
  int b  = r >> 15;
  const float* xb = x + (size_t)b * 65536;
  float acc = bias[co];
  #pragma unroll
  for (int k = 0; k < 4; ++k) {
    int gt = 2 * t - 1 + k;
    float xv = ((unsigned)gt < 65536u) ? xb[gt] : 0.f;
    acc += xv * w[k * 64 + co];
  }
  y[(size_t)idx] = fmaxf(acc, 0.f);
}

// ---------------- conv3: K=3, dil DIL, 64->64, relu, optional +res --------
// 512 thr = 8 waves; wave wv owns co0 = wv*8 (wave-uniform -> s_load weights);
// lane covers t = t0 + TPL*lane + i, i<TPL. grid (T/TT, 4).
template <int DIL, bool HAS_RES, int TT>
__global__ __launch_bounds__(512, 8) void conv3_kernel(
    const float* __restrict__ x, const float* __restrict__ w,
    const float* __restrict__ bias, const float* res,
    float* y, int T)
{
  constexpr int TPL = TT / 64;               // 1 or 2 t per lane
  constexpr int XT  = TT + 2 * DIL;
  constexpr int XS0 = (XT + 3) & ~3;
  constexpr int XS  = (XS0 % 8 == 4) ? XS0 : XS0 + 4;  // 8B-align rows, break pow2
  constexpr int NV  = TPL + 2 * DIL;
  __shared__ float xs[64 * XS];
  const int tid  = threadIdx.x;
  const int lane = tid & 63;
  const int b    = blockIdx.y;
  const int t0   = blockIdx.x * TT;
  const int wv   = __builtin_amdgcn_readfirstlane(tid >> 6);
  const int co0  = __builtin_amdgcn_readfirstlane(wv * 8);

  const float* xb = x + (size_t)b * T * 64;
  for (int e = tid; e < 16 * XT; e += 512) { // transpose to [ci][t]
    int tl = e >> 4, cq = (e & 15) * 4;
    int gt = t0 - DIL + tl;
    float4 v = make_float4(0.f, 0.f, 0.f, 0.f);
    if ((unsigned)gt < (unsigned)T) v = *(const float4*)&xb[(size_t)gt * 64 + cq];
    xs[(cq + 0) * XS + tl] = v.x;
    xs[(cq + 1) * XS + tl] = v.y;
    xs[(cq + 2) * XS + tl] = v.z;
    xs[(cq + 3) * XS + tl] = v.w;
  }
  __syncthreads();

  float acc[TPL][8] = {};
  const float* wb = w + co0;                 // w[k][ci][co0..co0+7]
  const int tb = TPL * lane;
  for (int ci = 0; ci < 64; ++ci) {
    const float* xr = xs + ci * XS + tb;
    float xv[NV];
    if constexpr (TPL == 2) {                // 8B-aligned -> ds_read_b64
      const float2* p2 = (const float2*)xr;
      #pragma unroll
      for (int q = 0; q < NV / 2; ++q) { float2 v = p2[q]; xv[2*q] = v.x; xv[2*q+1] = v.y; }
    } else {
      #pragma unroll
      for (int j = 0; j < NV; ++j) xv[j] = xr[j];
    }
    const float* w0 = wb + (0 * 64 + ci) * 64;
    const float* w1 = wb + (1 * 64 + ci) * 64;
    const float* w2 = wb + (2 * 64 + ci) * 64;
    #pragma unroll
    for (int j = 0; j < 8; ++j) {
      float c0 = w0[j], c1 = w1[j], c2 = w2[j];
      #pragma unroll
      for (int i = 0; i < TPL; ++i)
        acc[i][j] = fmaf(xv[i], c0, fmaf(xv[i + DIL], c1, fmaf(xv[i + 2 * DIL], c2, acc[i][j])));
    }
  }

  float bs[8];
  #pragma unroll
  for (int j = 0; j < 8; ++j) bs[j] = bias[co0 + j];
  #pragma unroll
  for (int i = 0; i < TPL; ++i) {
    size_t o = ((size_t)b * T + t0 + tb + i) * 64 + co0;
    float r[8];
    #pragma unroll
    for (int j = 0; j < 8; ++j) r[j] = fmaxf(acc[i][j] + bs[j], 0.f);
    if (HAS_RES) {
      float4 v0 = *(const float4*)&res[o];
      float4 v1 = *(const float4*)&res[o + 4];
      r[0] += v0.x; r[1] += v0.y; r[2] += v0.z; r[3] += v0.w;
      r[4] += v1.x; r[5] += v1.y; r[6] += v1.z; r[7] += v1.w;
    }
    *(float4*)&y[o]     = make_float4(r[0], r[1], r[2], r[3]);
    *(float4*)&y[o + 4] = make_float4(r[4], r[5], r[6], r[7]);
  }
}

// ---------------- down2: K=4 stride2, 64->64, relu ------------------------
__global__ __launch_bounds__(512, 8) void down2_kernel(
    const float* __restrict__ x, const float* __restrict__ w,
    const float* __restrict__ bias, float* __restrict__ y, int Tin)
{
  constexpr int XT = 130, XS = 132;          // XS mod 8 == 4
  __shared__ float xs[64 * XS];
  const int tid  = threadIdx.x;
  const int lane = tid & 63;
  const int b    = blockIdx.y;
  const int t0   = blockIdx.x * 64;
  const int Tout = Tin >> 1;
  const int wv   = __builtin_amdgcn_readfirstlane(tid >> 6);
  const int co0  = __builtin_amdgcn_readfirstlane(wv * 8);

  const float* xb = x + (size_t)b * Tin * 64;
  for (int e = tid; e < 16 * XT; e += 512) {
    int tl = e >> 4, cq = (e & 15) * 4;
    int gt = 2 * t0 - 1 + tl;
    float4 v = make_float4(0.f, 0.f, 0.f, 0.f);
    if ((unsigned)gt < (unsigned)Tin) v = *(const float4*)&xb[(size_t)gt * 64 + cq];
    xs[(cq + 0) * XS + tl] = v.x;
    xs[(cq + 1) * XS + tl] = v.y;
    xs[(cq + 2) * XS + tl] = v.z;
    xs[(cq + 3) * XS + tl] = v.w;
  }
  __syncthreads();

  float acc[8] = {};
  const float* wb = w + co0;
  for (int ci = 0; ci < 64; ++ci) {
    const float2* p2 = (const float2*)(xs + ci * XS + 2 * lane);
    float2 v0 = p2[0], v1 = p2[1];
    float a0 = v0.x, a1 = v0.y, a2 = v1.x, a3 = v1.y;
    const float* w0 = wb + (0 * 64 + ci) * 64;
    const float* w1 = wb + (1 * 64 + ci) * 64;
    const float* w2 = wb + (2 * 64 + ci) * 64;
    const float* w3 = wb + (3 * 64 + ci) * 64;
    #pragma unroll
    for (int j = 0; j < 8; ++j)
      acc[j] = fmaf(a0, w0[j], fmaf(a1, w1[j], fmaf(a2, w2[j], fmaf(a3, w3[j], acc[j]))));
  }

  size_t o = ((size_t)b * Tout + t0 + lane) * 64 + co0;
  #pragma unroll
  for (int q = 0; q < 2; ++q) {
    float4 rr;
    rr.x = fmaxf(acc[4*q+0] + bias[co0 + 4*q+0], 0.f);
    rr.y = fmaxf(acc[4*q+1] + bias[co0 + 4*q+1], 0.f);
    rr.z = fmaxf(acc[4*q+2] + bias[co0 + 4*q+2], 0.f);
    rr.w = fmaxf(acc[4*q+3] + bias[co0 + 4*q+3], 0.f);
    *(float4*)&y[o + 4 * q] = rr;
  }
}

// ---------------- up: conv_transpose K=4 stride2, 64->64, relu ------------
__global__ __launch_bounds__(512, 8) void up_kernel(
    const float* __restrict__ x, const float* __restrict__ w,
    const float* __restrict__ bias, float* __restrict__ y, int Tin)
{
  constexpr int XT = 66, XS = 68;            // XS mod 8 == 4
  __shared__ float xs[64 * XS];
  const int tid  = threadIdx.x;
  const int lane = tid & 63;
  const int b    = blockIdx.y;
  const int u0   = blockIdx.x * 64;
  const int Tout = Tin << 1;
  const int wv   = __builtin_amdgcn_readfirstlane(tid >> 6);
  const int co0  = __builtin_amdgcn_readfirstlane(wv * 8);

  const float* xb = x + (size_t)b * Tin * 64;
  for (int e = tid; e < 16 * XT; e += 512) {
    int ul = e >> 4, cq = (e & 15) * 4;
    int gu = u0 - 1 + ul;
    float4 v = make_float4(0.f, 0.f, 0.f, 0.f);
    if ((unsigned)gu < (unsigned)Tin) v = *(const float4*)&xb[(size_t)gu * 64 + cq];
    xs[(cq + 0) * XS + ul] = v.x;
    xs[(cq + 1) * XS + ul] = v.y;
    xs[(cq + 2) * XS + ul] = v.z;
    xs[(cq + 3) * XS + ul] = v.w;
  }
  __syncthreads();

  float acce[8] = {}, acco[8] = {};
  const float* wb = w + co0;
  for (int ci = 0; ci < 64; ++ci) {
    const float* xr = xs + ci * XS + lane;
    float a0 = xr[0], a1 = xr[1], a2 = xr[2];  // x[u-1], x[u], x[u+1]
    const float* w0 = wb + (0 * 64 + ci) * 64;
    const float* w1 = wb + (1 * 64 + ci) * 64;
    const float* w2 = wb + (2 * 64 + ci) * 64;
    const float* w3 = wb + (3 * 64 + ci) * 64;
    #pragma unroll
    for (int j = 0; j < 8; ++j) {
      acce[j] = fmaf(a0, w0[j], fmaf(a1, w2[j], acce[j]));
      acco[j] = fmaf(a1, w1[j], fmaf(a2, w3[j], acco[j]));
    }
  }

  size_t oe = ((size_t)b * Tout + 2 * (u0 + lane)) * 64 + co0;
  size_t oo = oe + 64;
  #pragma unroll
  for (int q = 0; q < 2; ++q) {
    float4 re, ro;
    re.x = fmaxf(acce[4*q+0] + bias[co0 + 4*q+0], 0.f);
    re.y = fmaxf(acce[4*q+1] + bias[co0 + 4*q+1], 0.f);
    re.z = fmaxf(acce[4*q+2] + bias[co0 + 4*q+2], 0.f);
    re.w = fmaxf(acce[4*q+3] + bias[co0 + 4*q+3], 0.f);
    ro.x = fmaxf(acco[4*q+0] + bias[co0 + 4*q+0], 0.f);
    ro.y = fmaxf(acco[4*q+1] + bias[co0 + 4*q+1], 0.f);
    ro.z = fmaxf(acco[4*q+2] + bias[co0 + 4*q+2], 0.f);
    ro.w = fmaxf(acco[4*q+3] + bias[co0 + 4*q+3], 0.f);
    *(float4*)&y[oe + 4 * q] = re;
    *(float4*)&y[oo + 4 * q] = ro;
  }
}

// ---------------- proj: K=3 dil1, 64->1, linear ---------------------------
__global__ __launch_bounds__(256) void proj_kernel(
    const float* __restrict__ x, const float* __restrict__ w,
    const float* __restrict__ bias, float* __restrict__ out)
{
  const int lane = threadIdx.x & 63;
  const int wid  = (blockIdx.x * 256 + threadIdx.x) >> 6;  // 4096 waves
  const float w0 = w[lane], w1 = w[64 + lane], w2 = w[128 + lane];
  const float bb = bias[0];
  size_t base = (size_t)wid * 64;
  for (int i = 0; i < 64; ++i) {
    size_t tau = base + i;
    int b = (int)(tau >> 16);
    int t = (int)(tau & 65535);
    const float* xb = x + ((size_t)b * 65536) * 64;
    float pm = (t > 0)     ? xb[(size_t)(t - 1) * 64 + lane] : 0.f;
    float pc =               xb[(size_t)t * 64 + lane];
    float pp = (t < 65535) ? xb[(size_t)(t + 1) * 64 + lane] : 0.f;
    float s = pm * w0 + pc * w1 + pp * w2;
    #pragma unroll
    for (int off = 32; off; off >>= 1) s += __shfl_down(s, off);
    if (lane == 0) out[tau] = s + bb;
  }
}

// ---------------- nz: per-token sum of squares ----------------------------
__global__ __launch_bounds__(256) void nz_kernel(
    const float* __restrict__ ze, float* __restrict__ nz)
{
  int lane = threadIdx.x & 63;
  int tok  = (blockIdx.x * 256 + threadIdx.x) >> 6;
  float v = ze[(size_t)tok * 64 + lane];
  float s = v * v;
  #pragma unroll
  for (int off = 32; off; off >>= 1) s += __shfl_down(s, off);
  if (lane == 0) nz[tok] = s;
}

// ---------------- ne: per-entry codebook norm (512 entries, once) ---------
__global__ __launch_bounds__(256) void ne_kernel(
    const float* __restrict__ cb, float* __restrict__ ne)
{
  int c = blockIdx.x * 256 + threadIdx.x;   // grid 2 -> 512 entries
  const float4* p = (const float4*)(cb + (size_t)c * 64);
  float s = 0.f;
  #pragma unroll
  for (int q = 0; q < 16; ++q) {
    float4 v = p[q];
    s += v.x * v.x + v.y * v.y + v.z * v.z + v.w * v.w;
  }
  ne[c] = s;
}

// ---------------- vq_dots: register-blocked GEMM --------------------------
// grid (512, 4): blockIdx.x = 64-token tile, blockIdx.y = 128-entry tile.
// 256 thr: tx = tid&15 -> 8 entries, ty = tid>>4 -> 4 tokens; acc[4][8].
// Inner loop per k: 1 zt b128 (broadcast x16) + 2 ct b128 + 32 FMA.
__global__ __launch_bounds__(256) void vq_dots_kernel(
    const float* __restrict__ ze, const float* __restrict__ cb,
    const float* __restrict__ nzbuf, const float* __restrict__ nebuf,
    float* __restrict__ sim_out, float2* __restrict__ pmin)
{
  constexpr int ZS = 68, CS = 132;           // strides: 16B-aligned, mod8==4
  __shared__ float zt[64 * ZS];              // [d][tok]   17.4 KB
  __shared__ float ct[64 * CS];              // [d][ent]   33.8 KB
  const int tid = threadIdx.x;
  const int tx  = tid & 15;                  // entry group (8 entries)
  const int ty  = tid >> 4;                  // token group (4 tokens)
  const int bx  = blockIdx.x, by = blockIdx.y;

  {                                          // stage z tile (transpose)
    const float* zb = ze + (size_t)bx * 64 * 64;
    #pragma unroll
    for (int it = 0; it < 4; ++it) {
      int e = tid + it * 256;
      int tl = e >> 4, cq = (e & 15) * 4;
      float4 v = *(const float4*)&zb[tl * 64 + cq];
      zt[(cq + 0) * ZS + tl] = v.x;
      zt[(cq + 1) * ZS + tl] = v.y;
      zt[(cq + 2) * ZS + tl] = v.z;
      zt[(cq + 3) * ZS + tl] = v.w;
    }
    const float* cbb = cb + (size_t)by * 128 * 64;
    #pragma unroll
    for (int it = 0; it < 8; ++it) {
      int e = tid + it * 256;
      int el = e >> 4, cq = (e & 15) * 4;
      float4 v = *(const float4*)&cbb[el * 64 + cq];
      ct[(cq + 0) * CS + el] = v.x;
      ct[(cq + 1) * CS + el] = v.y;
      ct[(cq + 2) * CS + el] = v.z;
      ct[(cq + 3) * CS + el] = v.w;
    }
  }
  __syncthreads();

  float acc[4][8] = {};
  #pragma unroll 4
  for (int k = 0; k < 64; ++k) {
    float4 zv = *(const float4*)&zt[k * ZS + ty * 4];
    float4 c0 = *(const float4*)&ct[k * CS + tx * 8];
    float4 c1 = *(const float4*)&ct[k * CS + tx * 8 + 4];
    float zr[4] = {zv.x, zv.y, zv.z, zv.w};
    float cr[8] = {c0.x, c0.y, c0.z, c0.w, c1.x, c1.y, c1.z, c1.w};
    #pragma unroll
    for (int i = 0; i < 4; ++i)
      #pragma unroll
      for (int j = 0; j < 8; ++j)
        acc[i][j] = fmaf(zr[i], cr[j], acc[i][j]);
  }

  // epilogue: dist, sim, argmin partials
  float4 nzq = *(const float4*)&nzbuf[bx * 64 + ty * 4];
  float nzv[4] = {nzq.x, nzq.y, nzq.z, nzq.w};
  float4 ne0  = *(const float4*)&nebuf[by * 128 + tx * 8];
  float4 ne1  = *(const float4*)&nebuf[by * 128 + tx * 8 + 4];
  float nev[8]  = {ne0.x, ne0.y, ne0.z, ne0.w, ne1.x, ne1.y, ne1.z, ne1.w};
  float rsne[8];
  #pragma unroll
  for (int j = 0; j < 8; ++j) rsne[j] = 1.f / sqrtf(nev[j]);
  const int ent0 = by * 128 + tx * 8;

  #pragma unroll
  for (int i = 0; i < 4; ++i) {
    const int tok = bx * 64 + ty * 4 + i;
    const float rsnz = 1.f / sqrtf(nzv[i]);
    float dist[8], simv[8];
    #pragma unroll
    for (int j = 0; j < 8; ++j) {
      dist[j] = (-2.f * acc[i][j] + nzv[i]) + nev[j];
      simv[j] = acc[i][j] * rsnz * rsne[j];
    }
    float* so = sim_out + (size_t)tok * 512 + ent0;
    *(float4*)&so[0] = make_float4(simv[0], simv[1], simv[2], simv[3]);
    *(float4*)&so[4] = make_float4(simv[4], simv[5], simv[6], simv[7]);

    float md = dist[0]; int mi = ent0;       // ascending strict < -> lowest j
    #pragma unroll
    for (int j = 1; j < 8; ++j)
      if (dist[j] < md) { md = dist[j]; mi = ent0 + j; }
    #pragma unroll
    for (int off = 1; off < 16; off <<= 1) { // reduce across 16-lane tx group
      float od = __shfl_xor(md, off);
      int   oi = __shfl_xor(mi, off);
      if (od < md || (od == md && oi < mi)) { md = od; mi = oi; }
    }
    if (tx == 0) pmin[tok * 4 + by] = make_float2(md, (float)mi);
  }
}

// ---------------- vq_finish: cross-partial argmin, z_q, ids, loss ---------
__global__ __launch_bounds__(256) void vq_finish_kernel(
    const float* __restrict__ ze, const float* __restrict__ cb,
    const float2* __restrict__ pmin, float* __restrict__ zq,
    float* __restrict__ ids_out, float* __restrict__ blocksum)
{
  const int tid = threadIdx.x;
  const int lane = tid & 63, wvid = tid >> 6;
  float lloss = 0.f;
  for (int it = 0; it < 16; ++it) {
    const int tok = blockIdx.x * 64 + wvid * 16 + it;
    float bd = 1e30f; int bi = 0;
    #pragma unroll
    for (int p = 0; p < 4; ++p) {            // 4 entry-tile partials, ascending
      float2 pr = pmin[tok * 4 + p];
      float d = pr.x; int i = (int)pr.y;
      if (d < bd || (d == bd && i < bi)) { bd = d; bi = i; }
    }
    float zev = ze[(size_t)tok * 64 + lane];
    float cv  = cb[(size_t)bi * 64 + lane];
    float df = zev - cv;
    float s = df * df;
    #pragma unroll
    for (int off = 32; off; off >>= 1) s += __shfl_down(s, off);
    zq[(size_t)tok * 64 + lane] = cv;
    if (lane == 0) { ids_out[tok] = (float)bi; lloss += sqrtf(s); }
  }
  __shared__ float ls[4];
  if (lane == 0) ls[wvid] = lloss;
  __syncthreads();
  if (tid == 0) blocksum[blockIdx.x] = ls[0] + ls[1] + ls[2] + ls[3];
}

__global__ void loss_fin_kernel(const float* __restrict__ blocksum,
                                float* __restrict__ out)
{
  const int lane = threadIdx.x;  // 64 threads
  float s = 0.f;
  for (int i = lane; i < 512; i += 64) s += blocksum[i];
  #pragma unroll
  for (int off = 32; off; off >>= 1) s += __shfl_down(s, off);
  if (lane == 0) out[0] = 1.25f * s / 32768.f;
}

// ---------------------------------------------------------------------------
#define LAUNCH_CONV3(DILV, RESV, XP, WP, BP, RP, YP)                           \
  do {                                                                         \
    if (T >= 16384)                                                            \
      conv3_kernel<DILV, RESV, 128><<<dim3(T / 128, 4), 512, 0, stream>>>(     \
          XP, WP, BP, RP, YP, T);                                              \
    else                                                                       \
      conv3_kernel<DILV, RESV, 64><<<dim3(T / 64, 4), 512, 0, stream>>>(       \
          XP, WP, BP, RP, YP, T);                                              \
  } while (0)

extern "C" void kernel_launch(void* const* d_in, const int* in_sizes, int n_in,
                              void* d_out, int out_size, void* d_ws, size_t ws_size,
                              hipStream_t stream)
{
  const float* x       = (const float*)d_in[0];
  const float* w_down0 = (const float*)d_in[1];
  const float* b_down0 = (const float*)d_in[2];
  const float* w_down  = (const float*)d_in[3];
  const float* b_down  = (const float*)d_in[4];
  const float* w_res_e = (const float*)d_in[5];
  const float* b_res_e = (const float*)d_in[6];
  const float* cb      = (const float*)d_in[7];
  const float* w_res_d = (const float*)d_in[8];
  const float* b_res_d = (const float*)d_in[9];
  const float* w_up    = (const float*)d_in[10];
  const float* b_up    = (const float*)d_in[11];
  const float* w_proj  = (const float*)d_in[12];
  const float* b_proj  = (const float*)d_in[13];

  float* out = (float*)d_out;
  const size_t BUF = (size_t)4 * 65536 * 64;
  float*  bufA     = (float*)d_ws;
  float*  bufB     = bufA + BUF;
  float*  nzbuf    = bufB + BUF;
  float*  nebuf    = nzbuf + 32768;
  float2* pmin     = (float2*)(nebuf + 512);
  float*  blocksum = (float*)(pmin + 32768 * 4);

  float* h = bufA;
  float* tmp = bufB;

  // ---- encoder ----
  down0_kernel<<<32768, 256, 0, stream>>>(x, w_down0, b_down0, h);
  int T = 32768;
  for (int blk = 0; blk < 3; ++blk) {
    if (blk > 0) {
      down2_kernel<<<dim3(T / 2 / 64, 4), 512, 0, stream>>>(
          h, w_down + (size_t)(blk - 1) * 4 * 64 * 64, b_down + (blk - 1) * 64, tmp, T);
      T >>= 1;
      float* s = h; h = tmp; tmp = s;
    }
    for (int r = 0; r < 4; ++r) {
      const float* w0p = w_res_e + (((size_t)blk * 4 + r) * 2 + 0) * 3 * 64 * 64;
      const float* w1p = w_res_e + (((size_t)blk * 4 + r) * 2 + 1) * 3 * 64 * 64;
      const float* b0p = b_res_e + (((size_t)blk * 4 + r) * 2 + 0) * 64;
      const float* b1p = b_res_e + (((size_t)blk * 4 + r) * 2 + 1) * 64;
      LAUNCH_CONV3(3, false, h, w0p, b0p, nullptr, tmp);
      LAUNCH_CONV3(1, true,  tmp, w1p, b1p, h, h);
    }
  }

  // ---- VQ (T == 8192, z_e in h; 32768 tokens) ----
  nz_kernel<<<8192, 256, 0, stream>>>(h, nzbuf);
  ne_kernel<<<2, 256, 0, stream>>>(cb, nebuf);
  vq_dots_kernel<<<dim3(512, 4), 256, 0, stream>>>(h, cb, nzbuf, nebuf, out + OFF_SIM, pmin);
  vq_finish_kernel<<<512, 256, 0, stream>>>(h, cb, pmin, tmp, out + OFF_IDS, blocksum);
  loss_fin_kernel<<<1, 64, 0, stream>>>(blocksum, out + OFF_LOSS);
  { float* s = h; h = tmp; tmp = s; }  // h = z_q

  // ---- decoder ----
  for (int blk = 0; blk < 3; ++blk) {
    for (int r = 0; r < 4; ++r) {
      const float* w0p = w_res_d + (((size_t)blk * 4 + r) * 2 + 0) * 3 * 64 * 64;
      const float* w1p = w_res_d + (((size_t)blk * 4 + r) * 2 + 1) * 3 * 64 * 64;
      const float* b0p = b_res_d + (((size_t)blk * 4 + r) * 2 + 0) * 64;
      const float* b1p = b_res_d + (((size_t)blk * 4 + r) * 2 + 1) * 64;
      LAUNCH_CONV3(1, false, h, w0p, b0p, nullptr, tmp);
      LAUNCH_CONV3(3, true,  tmp, w1p, b1p, h, h);
    }
    up_kernel<<<dim3(2 * T / 128, 4), 512, 0, stream>>>(
        h, w_up + (size_t)blk * 4 * 64 * 64, b_up + blk * 64, tmp, T);
    T <<= 1;
    float* s = h; h = tmp; tmp = s;
  }

  // ---- final projection (T == 65536) ----
  proj_kernel<<<1024, 256, 0, stream>>>(h, w_proj, b_proj, out);
}

// Round 3
// 1606.540 us; speedup vs baseline: 2.3135x; 1.0121x over previous
//
#include <hip/hip_runtime.h>
#include <cstdint>

// ---------------------------------------------------------------------------
// JukeboxAutoEncoder fp32, round 10.
// Change vs r9: per-row XOR column swizzle on ALL LDS staging transposes
//   (conv3/down2/up: swz=((row>>2)&7)<<1, bit0 untouched -> b64/float2 reads
//   stay aligned; vq_dots zt/ct: <<2, float4-aligned). Kills the 8-way
//   ds_write_b32 staging conflicts (up_kernel: 1.89M conflicts/dispatch,
//   bank = 16*(l&1)+tl because 4*XS = 16 mod 32). Row stride XS =
//   ((XT-1)|15)+1 so swizzled cols never cross rows.
// Output layout (flat f32): x_hat[262144] | loss_vq[1] | ids[32768] | sim[16777216]
// ---------------------------------------------------------------------------

#define OFF_LOSS 262144
#define OFF_IDS  262145
#define OFF_SIM  294913

// ---------------- down0: (B,65536,1) -> (B,32768,64), K=4 stride2, relu ----
__global__ __launch_bounds__(256) void down0_kernel(
    const float* __restrict__ x, const float* __restrict__ w,
    const float* __restrict__ bias, float* __restrict__ y)
{
  int idx = blockIdx.x * 256 + threadIdx.x;   // enumerates (b, t, co)
  int co = idx & 63;
  int r  = idx >> 6;
  int t  = r & 32767;
  int b  = r >> 15;
  const float* xb = x + (size_t)b * 65536;
  float acc = bias[co];
  #pragma unroll
  for (int k = 0; k < 4; ++k) {
    int gt = 2 * t - 1 + k;
    float xv = ((unsigned)gt < 65536u) ? xb[gt] : 0.f;
    acc += xv * w[k * 64 + co];
  }
  y[(size_t)idx] = fmaxf(acc, 0.f);
}

// ---------------- conv3: K=3, dil DIL, 64->64, relu, optional +res --------
// 512 thr = 8 waves; wave wv owns co0 = wv*8 (wave-uniform -> s_load weights);
// lane covers t = t0 + TPL*lane + i, i<TPL. grid (T/TT, 4).
template <int DIL, bool HAS_RES, int TT>
__global__ __launch_bounds__(512, 8) void conv3_kernel(
    const float* __restrict__ x, const float* __restrict__ w,
    const float* __restrict__ bias, const float* res,
    float* y, int T)
{
  constexpr int TPL = TT / 64;               // 1 or 2 t per lane
  constexpr int XT  = TT + 2 * DIL;
  constexpr int XS  = ((XT - 1) | 15) + 1;   // swizzle-safe row stride
  constexpr int NV  = TPL + 2 * DIL;
  __shared__ float xs[64 * XS];
  const int tid  = threadIdx.x;
  const int lane = tid & 63;
  const int b    = blockIdx.y;
  const int t0   = blockIdx.x * TT;
  const int wv   = __builtin_amdgcn_readfirstlane(tid >> 6);
  const int co0  = __builtin_amdgcn_readfirstlane(wv * 8);

  const float* xb = x + (size_t)b * T * 64;
  for (int e = tid; e < 16 * XT; e += 512) { // transpose to [ci][t], swizzled
    int tl = e >> 4, cq = (e & 15) * 4;
    int cs = tl ^ (((cq >> 2) & 7) << 1);    // rows cq..cq+3 share cq>>2
    int gt = t0 - DIL + tl;
    float4 v = make_float4(0.f, 0.f, 0.f, 0.f);
    if ((unsigned)gt < (unsigned)T) v = *(const float4*)&xb[(size_t)gt * 64 + cq];
    xs[(cq + 0) * XS + cs] = v.x;
    xs[(cq + 1) * XS + cs] = v.y;
    xs[(cq + 2) * XS + cs] = v.z;
    xs[(cq + 3) * XS + cs] = v.w;
  }
  __syncthreads();

  float acc[TPL][8] = {};
  const float* wb = w + co0;                 // w[k][ci][co0..co0+7]
  const int tb = TPL * lane;
  for (int ci = 0; ci < 64; ++ci) {
    const int swz = ((ci >> 2) & 7) << 1;
    const float* xr = xs + ci * XS;
    float xv[NV];
    if constexpr (TPL == 2) {                // 8B-aligned -> ds_read_b64
      #pragma unroll
      for (int q = 0; q < NV / 2; ++q) {
        float2 v = *(const float2*)&xr[(tb + 2 * q) ^ swz];
        xv[2*q] = v.x; xv[2*q+1] = v.y;
      }
    } else {
      #pragma unroll
      for (int j = 0; j < NV; ++j) xv[j] = xr[(tb + j) ^ swz];
    }
    const float* w0 = wb + (0 * 64 + ci) * 64;
    const float* w1 = wb + (1 * 64 + ci) * 64;
    const float* w2 = wb + (2 * 64 + ci) * 64;
    #pragma unroll
    for (int j = 0; j < 8; ++j) {
      float c0 = w0[j], c1 = w1[j], c2 = w2[j];
      #pragma unroll
      for (int i = 0; i < TPL; ++i)
        acc[i][j] = fmaf(xv[i], c0, fmaf(xv[i + DIL], c1, fmaf(xv[i + 2 * DIL], c2, acc[i][j])));
    }
  }

  float bs[8];
  #pragma unroll
  for (int j = 0; j < 8; ++j) bs[j] = bias[co0 + j];
  #pragma unroll
  for (int i = 0; i < TPL; ++i) {
    size_t o = ((size_t)b * T + t0 + tb + i) * 64 + co0;
    float r[8];
    #pragma unroll
    for (int j = 0; j < 8; ++j) r[j] = fmaxf(acc[i][j] + bs[j], 0.f);
    if (HAS_RES) {
      float4 v0 = *(const float4*)&res[o];
      float4 v1 = *(const float4*)&res[o + 4];
      r[0] += v0.x; r[1] += v0.y; r[2] += v0.z; r[3] += v0.w;
      r[4] += v1.x; r[5] += v1.y; r[6] += v1.z; r[7] += v1.w;
    }
    *(float4*)&y[o]     = make_float4(r[0], r[1], r[2], r[3]);
    *(float4*)&y[o + 4] = make_float4(r[4], r[5], r[6], r[7]);
  }
}

// ---------------- down2: K=4 stride2, 64->64, relu ------------------------
__global__ __launch_bounds__(512, 8) void down2_kernel(
    const float* __restrict__ x, const float* __restrict__ w,
    const float* __restrict__ bias, float* __restrict__ y, int Tin)
{
  constexpr int XT = 130, XS = 144;          // swizzle-safe stride
  __shared__ float xs[64 * XS];
  const int tid  = threadIdx.x;
  const int lane = tid & 63;
  const int b    = blockIdx.y;
  const int t0   = blockIdx.x * 64;
  const int Tout = Tin >> 1;
  const int wv   = __builtin_amdgcn_readfirstlane(tid >> 6);
  const int co0  = __builtin_amdgcn_readfirstlane(wv * 8);

  const float* xb = x + (size_t)b * Tin * 64;
  for (int e = tid; e < 16 * XT; e += 512) {
    int tl = e >> 4, cq = (e & 15) * 4;
    int cs = tl ^ (((cq >> 2) & 7) << 1);
    int gt = 2 * t0 - 1 + tl;
    float4 v = make_float4(0.f, 0.f, 0.f, 0.f);
    if ((unsigned)gt < (unsigned)Tin) v = *(const float4*)&xb[(size_t)gt * 64 + cq];
    xs[(cq + 0) * XS + cs] = v.x;
    xs[(cq + 1) * XS + cs] = v.y;
    xs[(cq + 2) * XS + cs] = v.z;
    xs[(cq + 3) * XS + cs] = v.w;
  }
  __syncthreads();

  float acc[8] = {};
  const float* wb = w + co0;
  for (int ci = 0; ci < 64; ++ci) {
    const int swz = ((ci >> 2) & 7) << 1;
    const float* xr = xs + ci * XS;
    float2 v0 = *(const float2*)&xr[(2 * lane) ^ swz];
    float2 v1 = *(const float2*)&xr[(2 * lane + 2) ^ swz];
    float a0 = v0.x, a1 = v0.y, a2 = v1.x, a3 = v1.y;
    const float* w0 = wb + (0 * 64 + ci) * 64;
    const float* w1 = wb + (1 * 64 + ci) * 64;
    const float* w2 = wb + (2 * 64 + ci) * 64;
    const float* w3 = wb + (3 * 64 + ci) * 64;
    #pragma unroll
    for (int j = 0; j < 8; ++j)
      acc[j] = fmaf(a0, w0[j], fmaf(a1, w1[j], fmaf(a2, w2[j], fmaf(a3, w3[j], acc[j]))));
  }

  size_t o = ((size_t)b * Tout + t0 + lane) * 64 + co0;
  #pragma unroll
  for (int q = 0; q < 2; ++q) {
    float4 rr;
    rr.x = fmaxf(acc[4*q+0] + bias[co0 + 4*q+0], 0.f);
    rr.y = fmaxf(acc[4*q+1] + bias[co0 + 4*q+1], 0.f);
    rr.z = fmaxf(acc[4*q+2] + bias[co0 + 4*q+2], 0.f);
    rr.w = fmaxf(acc[4*q+3] + bias[co0 + 4*q+3], 0.f);
    *(float4*)&y[o + 4 * q] = rr;
  }
}

// ---------------- up: conv_transpose K=4 stride2, 64->64, relu ------------
__global__ __launch_bounds__(512, 8) void up_kernel(
    const float* __restrict__ x, const float* __restrict__ w,
    const float* __restrict__ bias, float* __restrict__ y, int Tin)
{
  constexpr int XT = 66, XS = 80;            // swizzle-safe stride
  __shared__ float xs[64 * XS];
  const int tid  = threadIdx.x;
  const int lane = tid & 63;
  const int b    = blockIdx.y;
  const int u0   = blockIdx.x * 64;
  const int Tout = Tin << 1;
  const int wv   = __builtin_amdgcn_readfirstlane(tid >> 6);
  const int co0  = __builtin_amdgcn_readfirstlane(wv * 8);

  const float* xb = x + (size_t)b * Tin * 64;
  for (int e = tid; e < 16 * XT; e += 512) {
    int ul = e >> 4, cq = (e & 15) * 4;
    int cs = ul ^ (((cq >> 2) & 7) << 1);
    int gu = u0 - 1 + ul;
    float4 v = make_float4(0.f, 0.f, 0.f, 0.f);
    if ((unsigned)gu < (unsigned)Tin) v = *(const float4*)&xb[(size_t)gu * 64 + cq];
    xs[(cq + 0) * XS + cs] = v.x;
    xs[(cq + 1) * XS + cs] = v.y;
    xs[(cq + 2) * XS + cs] = v.z;
    xs[(cq + 3) * XS + cs] = v.w;
  }
  __syncthreads();

  float acce[8] = {}, acco[8] = {};
  const float* wb = w + co0;
  for (int ci = 0; ci < 64; ++ci) {
    const int swz = ((ci >> 2) & 7) << 1;
    const float* xr = xs + ci * XS;
    float a0 = xr[(lane) ^ swz];             // x[u-1]
    float a1 = xr[(lane + 1) ^ swz];         // x[u]
    float a2 = xr[(lane + 2) ^ swz];         // x[u+1]
    const float* w0 = wb + (0 * 64 + ci) * 64;
    const float* w1 = wb + (1 * 64 + ci) * 64;
    const float* w2 = wb + (2 * 64 + ci) * 64;
    const float* w3 = wb + (3 * 64 + ci) * 64;
    #pragma unroll
    for (int j = 0; j < 8; ++j) {
      acce[j] = fmaf(a0, w0[j], fmaf(a1, w2[j], acce[j]));
      acco[j] = fmaf(a1, w1[j], fmaf(a2, w3[j], acco[j]));
    }
  }

  size_t oe = ((size_t)b * Tout + 2 * (u0 + lane)) * 64 + co0;
  size_t oo = oe + 64;
  #pragma unroll
  for (int q = 0; q < 2; ++q) {
    float4 re, ro;
    re.x = fmaxf(acce[4*q+0] + bias[co0 + 4*q+0], 0.f);
    re.y = fmaxf(acce[4*q+1] + bias[co0 + 4*q+1], 0.f);
    re.z = fmaxf(acce[4*q+2] + bias[co0 + 4*q+2], 0.f);
    re.w = fmaxf(acce[4*q+3] + bias[co0 + 4*q+3], 0.f);
    ro.x = fmaxf(acco[4*q+0] + bias[co0 + 4*q+0], 0.f);
    ro.y = fmaxf(acco[4*q+1] + bias[co0 + 4*q+1], 0.f);
    ro.z = fmaxf(acco[4*q+2] + bias[co0 + 4*q+2], 0.f);
    ro.w = fmaxf(acco[4*q+3] + bias[co0 + 4*q+3], 0.f);
    *(float4*)&y[oe + 4 * q] = re;
    *(float4*)&y[oo + 4 * q] = ro;
  }
}

// ---------------- proj: K=3 dil1, 64->1, linear ---------------------------
__global__ __launch_bounds__(256) void proj_kernel(
    const float* __restrict__ x, const float* __restrict__ w,
    const float* __restrict__ bias, float* __restrict__ out)
{
  const int lane = threadIdx.x & 63;
  const int wid  = (blockIdx.x * 256 + threadIdx.x) >> 6;  // 4096 waves
  const float w0 = w[lane], w1 = w[64 + lane], w2 = w[128 + lane];
  const float bb = bias[0];
  size_t base = (size_t)wid * 64;
  for (int i = 0; i < 64; ++i) {
    size_t tau = base + i;
    int b = (int)(tau >> 16);
    int t = (int)(tau & 65535);
    const float* xb = x + ((size_t)b * 65536) * 64;
    float pm = (t > 0)     ? xb[(size_t)(t - 1) * 64 + lane] : 0.f;
    float pc =               xb[(size_t)t * 64 + lane];
    float pp = (t < 65535) ? xb[(size_t)(t + 1) * 64 + lane] : 0.f;
    float s = pm * w0 + pc * w1 + pp * w2;
    #pragma unroll
    for (int off = 32; off; off >>= 1) s += __shfl_down(s, off);
    if (lane == 0) out[tau] = s + bb;
  }
}

// ---------------- nz: per-token sum of squares ----------------------------
__global__ __launch_bounds__(256) void nz_kernel(
    const float* __restrict__ ze, float* __restrict__ nz)
{
  int lane = threadIdx.x & 63;
  int tok  = (blockIdx.x * 256 + threadIdx.x) >> 6;
  float v = ze[(size_t)tok * 64 + lane];
  float s = v * v;
  #pragma unroll
  for (int off = 32; off; off >>= 1) s += __shfl_down(s, off);
  if (lane == 0) nz[tok] = s;
}

// ---------------- ne: per-entry codebook norm (512 entries, once) ---------
__global__ __launch_bounds__(256) void ne_kernel(
    const float* __restrict__ cb, float* __restrict__ ne)
{
  int c = blockIdx.x * 256 + threadIdx.x;   // grid 2 -> 512 entries
  const float4* p = (const float4*)(cb + (size_t)c * 64);
  float s = 0.f;
  #pragma unroll
  for (int q = 0; q < 16; ++q) {
    float4 v = p[q];
    s += v.x * v.x + v.y * v.y + v.z * v.z + v.w * v.w;
  }
  ne[c] = s;
}

// ---------------- vq_dots: register-blocked GEMM --------------------------
// grid (512, 4): blockIdx.x = 64-token tile, blockIdx.y = 128-entry tile.
// 256 thr: tx = tid&15 -> 8 entries, ty = tid>>4 -> 4 tokens; acc[4][8].
// Staging writes swizzled (<<2, float4-aligned) like the convs.
__global__ __launch_bounds__(256) void vq_dots_kernel(
    const float* __restrict__ ze, const float* __restrict__ cb,
    const float* __restrict__ nzbuf, const float* __restrict__ nebuf,
    float* __restrict__ sim_out, float2* __restrict__ pmin)
{
  constexpr int ZS = 68, CS = 132;
  __shared__ float zt[64 * ZS];              // [d][tok]   17.4 KB
  __shared__ float ct[64 * CS];              // [d][ent]   33.8 KB
  const int tid = threadIdx.x;
  const int tx  = tid & 15;                  // entry group (8 entries)
  const int ty  = tid >> 4;                  // token group (4 tokens)
  const int bx  = blockIdx.x, by = blockIdx.y;

  {                                          // stage z tile (transpose, swz)
    const float* zb = ze + (size_t)bx * 64 * 64;
    #pragma unroll
    for (int it = 0; it < 4; ++it) {
      int e = tid + it * 256;
      int tl = e >> 4, cq = (e & 15) * 4;
      int cs = tl ^ (((cq >> 2) & 7) << 2);
      float4 v = *(const float4*)&zb[tl * 64 + cq];
      zt[(cq + 0) * ZS + cs] = v.x;
      zt[(cq + 1) * ZS + cs] = v.y;
      zt[(cq + 2) * ZS + cs] = v.z;
      zt[(cq + 3) * ZS + cs] = v.w;
    }
    const float* cbb = cb + (size_t)by * 128 * 64;
    #pragma unroll
    for (int it = 0; it < 8; ++it) {
      int e = tid + it * 256;
      int el = e >> 4, cq = (e & 15) * 4;
      int cs = el ^ (((cq >> 2) & 7) << 2);
      float4 v = *(const float4*)&cbb[el * 64 + cq];
      ct[(cq + 0) * CS + cs] = v.x;
      ct[(cq + 1) * CS + cs] = v.y;
      ct[(cq + 2) * CS + cs] = v.z;
      ct[(cq + 3) * CS + cs] = v.w;
    }
  }
  __syncthreads();

  float acc[4][8] = {};
  #pragma unroll 4
  for (int k = 0; k < 64; ++k) {
    const int swz = ((k >> 2) & 7) << 2;
    float4 zv = *(const float4*)&zt[k * ZS + ((ty * 4) ^ swz)];
    float4 c0 = *(const float4*)&ct[k * CS + ((tx * 8) ^ swz)];
    float4 c1 = *(const float4*)&ct[k * CS + ((tx * 8 + 4) ^ swz)];
    float zr[4] = {zv.x, zv.y, zv.z, zv.w};
    float cr[8] = {c0.x, c0.y, c0.z, c0.w, c1.x, c1.y, c1.z, c1.w};
    #pragma unroll
    for (int i = 0; i < 4; ++i)
      #pragma unroll
      for (int j = 0; j < 8; ++j)
        acc[i][j] = fmaf(zr[i], cr[j], acc[i][j]);
  }

  // epilogue: dist, sim, argmin partials
  float4 nzq = *(const float4*)&nzbuf[bx * 64 + ty * 4];
  float nzv[4] = {nzq.x, nzq.y, nzq.z, nzq.w};
  float4 ne0  = *(const float4*)&nebuf[by * 128 + tx * 8];
  float4 ne1  = *(const float4*)&nebuf[by * 128 + tx * 8 + 4];
  float nev[8]  = {ne0.x, ne0.y, ne0.z, ne0.w, ne1.x, ne1.y, ne1.z, ne1.w};
  float rsne[8];
  #pragma unroll
  for (int j = 0; j < 8; ++j) rsne[j] = 1.f / sqrtf(nev[j]);
  const int ent0 = by * 128 + tx * 8;

  #pragma unroll
  for (int i = 0; i < 4; ++i) {
    const int tok = bx * 64 + ty * 4 + i;
    const float rsnz = 1.f / sqrtf(nzv[i]);
    float dist[8], simv[8];
    #pragma unroll
    for (int j = 0; j < 8; ++j) {
      dist[j] = (-2.f * acc[i][j] + nzv[i]) + nev[j];
      simv[j] = acc[i][j] * rsnz * rsne[j];
    }
    float* so = sim_out + (size_t)tok * 512 + ent0;
    *(float4*)&so[0] = make_float4(simv[0], simv[1], simv[2], simv[3]);
    *(float4*)&so[4] = make_float4(simv[4], simv[5], simv[6], simv[7]);

    float md = dist[0]; int mi = ent0;       // ascending strict < -> lowest j
    #pragma unroll
    for (int j = 1; j < 8; ++j)
      if (dist[j] < md) { md = dist[j]; mi = ent0 + j; }
    #pragma unroll
    for (int off = 1; off < 16; off <<= 1) { // reduce across 16-lane tx group
      float od = __shfl_xor(md, off);
      int   oi = __shfl_xor(mi, off);
      if (od < md || (od == md && oi < mi)) { md = od; mi = oi; }
    }
    if (tx == 0) pmin[tok * 4 + by] = make_float2(md, (float)mi);
  }
}

// ---------------- vq_finish: cross-partial argmin, z_q, ids, loss ---------
__global__ __launch_bounds__(256) void vq_finish_kernel(
    const float* __restrict__ ze, const float* __restrict__ cb,
    const float2* __restrict__ pmin, float* __restrict__ zq,
    float* __restrict__ ids_out, float* __restrict__ blocksum)
{
  const int tid = threadIdx.x;
  const int lane = tid & 63, wvid = tid >> 6;
  float lloss = 0.f;
  for (int it = 0; it < 16; ++it) {
    const int tok = blockIdx.x * 64 + wvid * 16 + it;
    float bd = 1e30f; int bi = 0;
    #pragma unroll
    for (int p = 0; p < 4; ++p) {            // 4 entry-tile partials, ascending
      float2 pr = pmin[tok * 4 + p];
      float d = pr.x; int i = (int)pr.y;
      if (d < bd || (d == bd && i < bi)) { bd = d; bi = i; }
    }
    float zev = ze[(size_t)tok * 64 + lane];
    float cv  = cb[(size_t)bi * 64 + lane];
    float df = zev - cv;
    float s = df * df;
    #pragma unroll
    for (int off = 32; off; off >>= 1) s += __shfl_down(s, off);
    zq[(size_t)tok * 64 + lane] = cv;
    if (lane == 0) { ids_out[tok] = (float)bi; lloss += sqrtf(s); }
  }
  __shared__ float ls[4];
  if (lane == 0) ls[wvid] = lloss;
  __syncthreads();
  if (tid == 0) blocksum[blockIdx.x] = ls[0] + ls[1] + ls[2] + ls[3];
}

__global__ void loss_fin_kernel(const float* __restrict__ blocksum,
                                float* __restrict__ out)
{
  const int lane = threadIdx.x;  // 64 threads
  float s = 0.f;
  for (int i = lane; i < 512; i += 64) s += blocksum[i];
  #pragma unroll
  for (int off = 32; off; off >>= 1) s += __shfl_down(s, off);
  if (lane == 0) out[0] = 1.25f * s / 32768.f;
}

// ---------------------------------------------------------------------------
#define LAUNCH_CONV3(DILV, RESV, XP, WP, BP, RP, YP)                           \
  do {                                                                         \
    if (T >= 16384)                                                            \
      conv3_kernel<DILV, RESV, 128><<<dim3(T / 128, 4), 512, 0, stream>>>(     \
          XP, WP, BP, RP, YP, T);                                              \
    else                                                                       \
      conv3_kernel<DILV, RESV, 64><<<dim3(T / 64, 4), 512, 0, stream>>>(       \
          XP, WP, BP, RP, YP, T);                                              \
  } while (0)

extern "C" void kernel_launch(void* const* d_in, const int* in_sizes, int n_in,
                              void* d_out, int out_size, void* d_ws, size_t ws_size,
                              hipStream_t stream)
{
  const float* x       = (const float*)d_in[0];
  const float* w_down0 = (const float*)d_in[1];
  const float* b_down0 = (const float*)d_in[2];
  const float* w_down  = (const float*)d_in[3];
  const float* b_down  = (const float*)d_in[4];
  const float* w_res_e = (const float*)d_in[5];
  const float* b_res_e = (const float*)d_in[6];
  const float* cb      = (const float*)d_in[7];
  const float* w_res_d = (const float*)d_in[8];
  const float* b_res_d = (const float*)d_in[9];
  const float* w_up    = (const float*)d_in[10];
  const float* b_up    = (const float*)d_in[11];
  const float* w_proj  = (const float*)d_in[12];
  const float* b_proj  = (const float*)d_in[13];

  float* out = (float*)d_out;
  const size_t BUF = (size_t)4 * 65536 * 64;
  float*  bufA     = (float*)d_ws;
  float*  bufB     = bufA + BUF;
  float*  nzbuf    = bufB + BUF;
  float*  nebuf    = nzbuf + 32768;
  float2* pmin     = (float2*)(nebuf + 512);
  float*  blocksum = (float*)(pmin + 32768 * 4);

  float* h = bufA;
  float* tmp = bufB;

  // ---- encoder ----
  down0_kernel<<<32768, 256, 0, stream>>>(x, w_down0, b_down0, h);
  int T = 32768;
  for (int blk = 0; blk < 3; ++blk) {
    if (blk > 0) {
      down2_kernel<<<dim3(T / 2 / 64, 4), 512, 0, stream>>>(
          h, w_down + (size_t)(blk - 1) * 4 * 64 * 64, b_down + (blk - 1) * 64, tmp, T);
      T >>= 1;
      float* s = h; h = tmp; tmp = s;
    }
    for (int r = 0; r < 4; ++r) {
      const float* w0p = w_res_e + (((size_t)blk * 4 + r) * 2 + 0) * 3 * 64 * 64;
      const float* w1p = w_res_e + (((size_t)blk * 4 + r) * 2 + 1) * 3 * 64 * 64;
      const float* b0p = b_res_e + (((size_t)blk * 4 + r) * 2 + 0) * 64;
      const float* b1p = b_res_e + (((size_t)blk * 4 + r) * 2 + 1) * 64;
      LAUNCH_CONV3(3, false, h, w0p, b0p, nullptr, tmp);
      LAUNCH_CONV3(1, true,  tmp, w1p, b1p, h, h);
    }
  }

  // ---- VQ (T == 8192, z_e in h; 32768 tokens) ----
  nz_kernel<<<8192, 256, 0, stream>>>(h, nzbuf);
  ne_kernel<<<2, 256, 0, stream>>>(cb, nebuf);
  vq_dots_kernel<<<dim3(512, 4), 256, 0, stream>>>(h, cb, nzbuf, nebuf, out + OFF_SIM, pmin);
  vq_finish_kernel<<<512, 256, 0, stream>>>(h, cb, pmin, tmp, out + OFF_IDS, blocksum);
  loss_fin_kernel<<<1, 64, 0, stream>>>(blocksum, out + OFF_LOSS);
  { float* s = h; h = tmp; tmp = s; }  // h = z_q

  // ---- decoder ----
  for (int blk = 0; blk < 3; ++blk) {
    for (int r = 0; r < 4; ++r) {
      const float* w0p = w_res_d + (((size_t)blk * 4 + r) * 2 + 0) * 3 * 64 * 64;
      const float* w1p = w_res_d + (((size_t)blk * 4 + r) * 2 + 1) * 3 * 64 * 64;
      const float* b0p = b_res_d + (((size_t)blk * 4 + r) * 2 + 0) * 64;
      const float* b1p = b_res_d + (((size_t)blk * 4 + r) * 2 + 1) * 64;
      LAUNCH_CONV3(1, false, h, w0p, b0p, nullptr, tmp);
      LAUNCH_CONV3(3, true,  tmp, w1p, b1p, h, h);
    }
    up_kernel<<<dim3(2 * T / 128, 4), 512, 0, stream>>>(
        h, w_up + (size_t)blk * 4 * 64 * 64, b_up + blk * 64, tmp, T);
    T <<= 1;
    float* s = h; h = tmp; tmp = s;
  }

  // ---- final projection (T == 65536) ----
  proj_kernel<<<1024, 256, 0, stream>>>(h, w_proj, b_proj, out);
}